// Round 1
// baseline (535.735 us; speedup 1.0000x reference)
//
#include <hip/hip_runtime.h>

typedef unsigned short u16;
typedef short s16x8 __attribute__((ext_vector_type(8)));
typedef float f32x4 __attribute__((ext_vector_type(4)));

#define B_SZ 8
#define LQ 2048
#define LK 2048
#define HD 1024

#define BM 128
#define BN 128
#define BK 32

__device__ __forceinline__ u16 f32_to_bf16(float x) {
  unsigned u = __float_as_uint(x);
  u += 0x7fffu + ((u >> 16) & 1u);
  return (u16)(u >> 16);
}
__device__ __forceinline__ float bf16_to_f32(u16 h) {
  return __uint_as_float(((unsigned)h) << 16);
}

__device__ __forceinline__ void gload_lds16(const void* g, void* l) {
  __builtin_amdgcn_global_load_lds(
      (__attribute__((address_space(1))) void*)(g),
      (__attribute__((address_space(3))) void*)(l), 16, 0, 0);
}

// ---------------------------------------------------------------------------
// fp32 -> bf16 hi/lo split (elementwise, float4-vectorized)
// ---------------------------------------------------------------------------
__global__ __launch_bounds__(256)
void split_bf16_k(const float4* __restrict__ x, ushort4* __restrict__ hi,
                  ushort4* __restrict__ lo, int n4)
{
  int i = blockIdx.x * blockDim.x + threadIdx.x;
  int stride = gridDim.x * blockDim.x;
  for (; i < n4; i += stride) {
    float4 f = x[i];
    ushort4 h, l;
    h.x = f32_to_bf16(f.x); l.x = f32_to_bf16(f.x - bf16_to_f32(h.x));
    h.y = f32_to_bf16(f.y); l.y = f32_to_bf16(f.y - bf16_to_f32(h.y));
    h.z = f32_to_bf16(f.z); l.z = f32_to_bf16(f.z - bf16_to_f32(h.z));
    h.w = f32_to_bf16(f.w); l.w = f32_to_bf16(f.w - bf16_to_f32(h.w));
    hi[i] = h; lo[i] = l;
  }
}

// ---------------------------------------------------------------------------
// V [B][LK][HD] fp32 -> Vt [B][HD][LK] bf16 (32x32 LDS tile transpose)
// ---------------------------------------------------------------------------
__global__ __launch_bounds__(256)
void vtrans_k(const float* __restrict__ V, u16* __restrict__ Vt)
{
  __shared__ float t[32][33];
  int z = blockIdx.z;
  int tx = threadIdx.x, ty = threadIdx.y;
  int h0 = blockIdx.x * 32, k0 = blockIdx.y * 32;
  const float* Vb = V + (size_t)z * LK * HD;
  u16* Vtb = Vt + (size_t)z * HD * LK;
#pragma unroll
  for (int i = 0; i < 4; ++i)
    t[ty + i * 8][tx] = Vb[(size_t)(k0 + ty + i * 8) * HD + h0 + tx];
  __syncthreads();
#pragma unroll
  for (int i = 0; i < 4; ++i)
    Vtb[(size_t)(h0 + ty + i * 8) * LK + k0 + tx] = f32_to_bf16(t[tx][ty + i * 8]);
}

// ---------------------------------------------------------------------------
// B^T-layout GEMM: C[m,n] = sum_k A[m,k] * Bt[n,k]
//   SPLIT==3: C = Ah*Bh + Al*Bh + Ah*Bl   (fp32-grade precision)
//   SPLIT==1: C = Ah*Bh
//   MODE==0:  C += bias[n]; store bf16 hi/lo into Ch/Cl (ld = N)
//   MODE==1:  store fp32 into Cf (per-batch stride batchC, ld = N)
// 128x128 tile, BK=32, 4 waves (2x2), 4x4 16x16x32 frags per wave.
// LDS staged via global_load_lds width-16; (row&3) XOR slot swizzle applied
// on the GLOBAL source (LDS stays lane-linear) and undone on the ds_read.
// ---------------------------------------------------------------------------
template<int SPLIT, int MODE>
__global__ __launch_bounds__(256, 2)
void gemm_bt(const u16* __restrict__ Ah, const u16* __restrict__ Al,
             const u16* __restrict__ Bh, const u16* __restrict__ Bl,
             const float* __restrict__ bias,
             float* __restrict__ Cf, u16* __restrict__ Ch, u16* __restrict__ Cl,
             int M, int N, int K,
             long batchA, long batchB, long batchC)
{
  extern __shared__ u16 smem[];
  u16* sAh = smem;                 // BM*BK
  u16* sBh = smem + BM * BK;       // BN*BK
  u16* sAl = smem + 2 * BM * BK;   // SPLIT==3 only
  u16* sBl = smem + 3 * BM * BK;

  const int z = blockIdx.z;
  const u16* pAh = Ah + (size_t)z * batchA;
  const u16* pBh = Bh + (size_t)z * batchB;
  const u16* pAl = (SPLIT == 3) ? (Al + (size_t)z * batchA) : nullptr;
  const u16* pBl = (SPLIT == 3) ? (Bl + (size_t)z * batchB) : nullptr;

  const int tid = threadIdx.x;
  const int lane = tid & 63;
  const int wave = tid >> 6;
  const int wm = (wave >> 1) * 64;
  const int wn = (wave & 1) * 64;
  const int m0 = blockIdx.x * BM;
  const int n0 = blockIdx.y * BN;
  const int lr = lane & 15;   // frag row/col
  const int ls = lane >> 4;   // k-slot (8 elems each)

  f32x4 acc[4][4];
  const f32x4 zero4 = {0.f, 0.f, 0.f, 0.f};
#pragma unroll
  for (int i = 0; i < 4; ++i)
#pragma unroll
    for (int j = 0; j < 4; ++j)
      acc[i][j] = zero4;

  // staging coords: chunk c covers LDS bytes [c*16, c*16+16) = tile row c>>2,
  // 16B slot c&3.  Source column is slot XOR (row&3) -> LDS holds swizzled.
  const int c0 = tid, c1 = tid + 256;
  const int r0 = c0 >> 2, r1 = c1 >> 2;
  const int g0 = (((c0 & 3) ^ (r0 & 3)) << 3);
  const int g1 = (((c1 & 3) ^ (r1 & 3)) << 3);

  for (int kt = 0; kt < K; kt += BK) {
    size_t a0 = (size_t)(m0 + r0) * K + kt + g0;
    size_t a1 = (size_t)(m0 + r1) * K + kt + g1;
    size_t b0 = (size_t)(n0 + r0) * K + kt + g0;
    size_t b1 = (size_t)(n0 + r1) * K + kt + g1;
    gload_lds16(pAh + a0, sAh + c0 * 8);
    gload_lds16(pAh + a1, sAh + c1 * 8);
    gload_lds16(pBh + b0, sBh + c0 * 8);
    gload_lds16(pBh + b1, sBh + c1 * 8);
    if (SPLIT == 3) {
      gload_lds16(pAl + a0, sAl + c0 * 8);
      gload_lds16(pAl + a1, sAl + c1 * 8);
      gload_lds16(pBl + b0, sBl + c0 * 8);
      gload_lds16(pBl + b1, sBl + c1 * 8);
    }
    __syncthreads();   // compiler inserts vmcnt(0) drain before s_barrier

    s16x8 a_h[4], a_l[4];
#pragma unroll
    for (int mi = 0; mi < 4; ++mi) {
      int rr = wm + mi * 16 + lr;
      int off = rr * BK + ((ls ^ (rr & 3)) << 3);
      a_h[mi] = *(const s16x8*)(sAh + off);
      if (SPLIT == 3) a_l[mi] = *(const s16x8*)(sAl + off);
    }
#pragma unroll
    for (int ni = 0; ni < 4; ++ni) {
      int rr = wn + ni * 16 + lr;
      int off = rr * BK + ((ls ^ (rr & 3)) << 3);
      s16x8 b_h = *(const s16x8*)(sBh + off);
#pragma unroll
      for (int mi = 0; mi < 4; ++mi)
        acc[mi][ni] = __builtin_amdgcn_mfma_f32_16x16x32_bf16(a_h[mi], b_h, acc[mi][ni], 0, 0, 0);
      if (SPLIT == 3) {
        s16x8 b_l = *(const s16x8*)(sBl + off);
#pragma unroll
        for (int mi = 0; mi < 4; ++mi) {
          acc[mi][ni] = __builtin_amdgcn_mfma_f32_16x16x32_bf16(a_l[mi], b_h, acc[mi][ni], 0, 0, 0);
          acc[mi][ni] = __builtin_amdgcn_mfma_f32_16x16x32_bf16(a_h[mi], b_l, acc[mi][ni], 0, 0, 0);
        }
      }
    }
    __syncthreads();
  }

  // epilogue: C/D layout (verified m89/m91): col = lane&15, row = (lane>>4)*4 + r
#pragma unroll
  for (int mi = 0; mi < 4; ++mi) {
#pragma unroll
    for (int ni = 0; ni < 4; ++ni) {
#pragma unroll
      for (int r = 0; r < 4; ++r) {
        int row = m0 + wm + mi * 16 + ls * 4 + r;
        int col = n0 + wn + ni * 16 + lr;
        float v = acc[mi][ni][r];
        if (MODE == 0) {
          v += bias[col];
          u16 h = f32_to_bf16(v);
          u16 l = f32_to_bf16(v - bf16_to_f32(h));
          size_t idx = (size_t)row * N + col;
          Ch[idx] = h;
          Cl[idx] = l;
        } else {
          Cf[(size_t)z * batchC + (size_t)row * N + col] = v;
        }
      }
    }
  }
}

// ---------------------------------------------------------------------------
// row softmax over Lk=2048, in place (fp32) + bf16 copy. 1 block (256t) / row.
// ---------------------------------------------------------------------------
__global__ __launch_bounds__(256)
void softmax_k(float* __restrict__ sc, u16* __restrict__ pbf)
{
  __shared__ float redm[4], reds[4];
  size_t row = blockIdx.x;
  float* rp = sc + row * (size_t)LK;
  int tid = threadIdx.x;
  int lane = tid & 63, wv = tid >> 6;

  float4 v0 = *(const float4*)(rp + tid * 8);
  float4 v1 = *(const float4*)(rp + tid * 8 + 4);

  float m = fmaxf(fmaxf(fmaxf(v0.x, v0.y), fmaxf(v0.z, v0.w)),
                  fmaxf(fmaxf(v1.x, v1.y), fmaxf(v1.z, v1.w)));
#pragma unroll
  for (int off = 32; off > 0; off >>= 1)
    m = fmaxf(m, __shfl_xor(m, off));
  if (lane == 0) redm[wv] = m;
  __syncthreads();
  m = fmaxf(fmaxf(redm[0], redm[1]), fmaxf(redm[2], redm[3]));

  float e[8];
  e[0] = __expf(v0.x - m); e[1] = __expf(v0.y - m);
  e[2] = __expf(v0.z - m); e[3] = __expf(v0.w - m);
  e[4] = __expf(v1.x - m); e[5] = __expf(v1.y - m);
  e[6] = __expf(v1.z - m); e[7] = __expf(v1.w - m);
  float s = ((e[0] + e[1]) + (e[2] + e[3])) + ((e[4] + e[5]) + (e[6] + e[7]));
#pragma unroll
  for (int off = 32; off > 0; off >>= 1)
    s += __shfl_xor(s, off);
  if (lane == 0) reds[wv] = s;
  __syncthreads();
  s = (reds[0] + reds[1]) + (reds[2] + reds[3]);

  float inv = 1.0f / s;
  float4 p0 = {e[0] * inv, e[1] * inv, e[2] * inv, e[3] * inv};
  float4 p1 = {e[4] * inv, e[5] * inv, e[6] * inv, e[7] * inv};
  *(float4*)(rp + tid * 8) = p0;
  *(float4*)(rp + tid * 8 + 4) = p1;

  u16* pb = pbf + row * (size_t)LK + tid * 8;
  ushort4 h0, h1;
  h0.x = f32_to_bf16(p0.x); h0.y = f32_to_bf16(p0.y);
  h0.z = f32_to_bf16(p0.z); h0.w = f32_to_bf16(p0.w);
  h1.x = f32_to_bf16(p1.x); h1.y = f32_to_bf16(p1.y);
  h1.z = f32_to_bf16(p1.z); h1.w = f32_to_bf16(p1.w);
  *(ushort4*)(pb) = h0;
  *(ushort4*)(pb + 4) = h1;
}

// ---------------------------------------------------------------------------
extern "C" void kernel_launch(void* const* d_in, const int* in_sizes, int n_in,
                              void* d_out, int out_size, void* d_ws, size_t ws_size,
                              hipStream_t stream)
{
  const float* q  = (const float*)d_in[0];
  const float* ky = (const float*)d_in[1];
  const float* vv = (const float*)d_in[2];
  const float* Ww = (const float*)d_in[3];
  const float* Wb = (const float*)d_in[4];
  float* out   = (float*)d_out;                       // [8,2048,1024]
  float* pattn = out + (size_t)B_SZ * LQ * HD;        // [8,2048,2048]

  char* ws = (char*)d_ws;
  const size_t SZ_Q = (size_t)B_SZ * LQ * HD * 2;     // 33,554,432 B
  u16* qh  = (u16*)(ws);
  u16* ql  = (u16*)(ws + SZ_Q);
  u16* kh  = (u16*)(ws + 2 * SZ_Q);
  u16* kl  = (u16*)(ws + 3 * SZ_Q);
  u16* vt  = (u16*)(ws + 4 * SZ_Q);
  u16* wh  = (u16*)(ws + 5 * SZ_Q);
  u16* wl  = (u16*)(ws + 5 * SZ_Q + 2097152);
  u16* qph = (u16*)(ws + 5 * SZ_Q + 4194304);
  u16* qpl = (u16*)(ws + 6 * SZ_Q + 4194304);
  u16* pbf = (u16*)(ws);   // reuses qh+ql region (dead after GEMM1)

  const int nq4 = (int)((size_t)B_SZ * LQ * HD / 4);  // 4,194,304
  const int nw4 = HD * HD / 4;                        // 262,144

  split_bf16_k<<<2048, 256, 0, stream>>>((const float4*)q,  (ushort4*)qh, (ushort4*)ql, nq4);
  split_bf16_k<<<2048, 256, 0, stream>>>((const float4*)ky, (ushort4*)kh, (ushort4*)kl, nq4);
  split_bf16_k<<<1024, 256, 0, stream>>>((const float4*)Ww, (ushort4*)wh, (ushort4*)wl, nw4);
  vtrans_k<<<dim3(HD / 32, LK / 32, B_SZ), dim3(32, 8), 0, stream>>>(vv, vt);

  // GEMM1: q_proj = q @ W^T + b  ->  bf16 hi/lo
  gemm_bt<3, 0><<<dim3(16384 / BM, HD / BN, 1), 256, 4 * BM * BK * 2, stream>>>(
      qh, ql, wh, wl, Wb, nullptr, qph, qpl,
      B_SZ * LQ, HD, HD, 0, 0, 0);

  // GEMM2: scores = q_proj @ key^T  -> fp32 straight into p_attn region
  gemm_bt<3, 1><<<dim3(LQ / BM, LK / BN, B_SZ), 256, 4 * BM * BK * 2, stream>>>(
      qph, qpl, kh, kl, nullptr, pattn, nullptr, nullptr,
      LQ, LK, HD, (long)LQ * HD, (long)LK * HD, (long)LQ * LK);

  // softmax rows, in place + bf16 copy for PV
  softmax_k<<<B_SZ * LQ, 256, 0, stream>>>(pattn, pbf);

  // GEMM3: out = p @ V   (Vt is [HD][LK] per batch -> B^T layout)
  gemm_bt<1, 1><<<dim3(LQ / BM, HD / BN, B_SZ), 256, 2 * BM * BK * 2, stream>>>(
      pbf, nullptr, vt, nullptr, nullptr, out, nullptr, nullptr,
      LQ, HD, LK, (long)LQ * LK, (long)HD * LK, (long)LQ * HD);
}

// Round 2
// 447.420 us; speedup vs baseline: 1.1974x; 1.1974x over previous
//
#include <hip/hip_runtime.h>

typedef unsigned short u16;
typedef _Float16 f16;
typedef f16 f16x8 __attribute__((ext_vector_type(8)));
typedef float f32x4 __attribute__((ext_vector_type(4)));

#define B_SZ 8
#define LQ 2048
#define LK 2048
#define HD 1024

#define BM 128
#define BN 128
#define BK 32

__device__ __forceinline__ u16 f32_to_f16(float x) {
  f16 h = (f16)x;
  return __builtin_bit_cast(u16, h);
}
__device__ __forceinline__ float f16_to_f32(u16 h) {
  return (float)__builtin_bit_cast(f16, h);
}

__device__ __forceinline__ void gload_lds16(const void* g, void* l) {
  __builtin_amdgcn_global_load_lds(
      (__attribute__((address_space(1))) void*)(g),
      (__attribute__((address_space(3))) void*)(l), 16, 0, 0);
}

// ---------------------------------------------------------------------------
// fp32 -> fp16 hi/lo split (elementwise, float4-vectorized)
// ---------------------------------------------------------------------------
__global__ __launch_bounds__(256)
void split_f16_k(const float4* __restrict__ x, ushort4* __restrict__ hi,
                 ushort4* __restrict__ lo, int n4)
{
  int i = blockIdx.x * blockDim.x + threadIdx.x;
  int stride = gridDim.x * blockDim.x;
  for (; i < n4; i += stride) {
    float4 f = x[i];
    ushort4 h, l;
    h.x = f32_to_f16(f.x); l.x = f32_to_f16(f.x - f16_to_f32(h.x));
    h.y = f32_to_f16(f.y); l.y = f32_to_f16(f.y - f16_to_f32(h.y));
    h.z = f32_to_f16(f.z); l.z = f32_to_f16(f.z - f16_to_f32(h.z));
    h.w = f32_to_f16(f.w); l.w = f32_to_f16(f.w - f16_to_f32(h.w));
    hi[i] = h; lo[i] = l;
  }
}

// fp32 -> fp16 single
__global__ __launch_bounds__(256)
void cvt_f16_k(const float4* __restrict__ x, ushort4* __restrict__ o, int n4)
{
  int i = blockIdx.x * blockDim.x + threadIdx.x;
  int stride = gridDim.x * blockDim.x;
  for (; i < n4; i += stride) {
    float4 f = x[i];
    ushort4 h;
    h.x = f32_to_f16(f.x); h.y = f32_to_f16(f.y);
    h.z = f32_to_f16(f.z); h.w = f32_to_f16(f.w);
    o[i] = h;
  }
}

// ---------------------------------------------------------------------------
// V [B][LK][HD] fp32 -> Vt [B][HD][LK] fp16 (32x32 LDS tile transpose)
// ---------------------------------------------------------------------------
__global__ __launch_bounds__(256)
void vtrans_k(const float* __restrict__ V, u16* __restrict__ Vt)
{
  __shared__ float t[32][33];
  int z = blockIdx.z;
  int tx = threadIdx.x, ty = threadIdx.y;
  int h0 = blockIdx.x * 32, k0 = blockIdx.y * 32;
  const float* Vb = V + (size_t)z * LK * HD;
  u16* Vtb = Vt + (size_t)z * HD * LK;
#pragma unroll
  for (int i = 0; i < 4; ++i)
    t[ty + i * 8][tx] = Vb[(size_t)(k0 + ty + i * 8) * HD + h0 + tx];
  __syncthreads();
#pragma unroll
  for (int i = 0; i < 4; ++i)
    Vtb[(size_t)(h0 + ty + i * 8) * LK + k0 + tx] = f32_to_f16(t[tx][ty + i * 8]);
}

// ---------------------------------------------------------------------------
// B^T-layout GEMM: C[m,n] = sum_k A[m,k] * Bt[n,k]   (fp16 MFMA)
//   SPLIT==2: C = Ah*B + Al*B  (A fp16 hi/lo, B fp16 single -> ~fp32 grade)
//   SPLIT==1: C = Ah*B
//   MODE==0:  C += bias[n]; store fp16 hi/lo into Ch/Cl (ld = N)
//   MODE==1:  store fp32 into Cf (per-batch stride batchC, ld = N)
// 128x128 tile, BK=32, 4 waves (2x2), 4x4 16x16x32 frags per wave.
// LDS staged via global_load_lds width-16; (row&3) XOR slot swizzle applied
// on the GLOBAL source (LDS stays lane-linear) and undone on the ds_read.
// ---------------------------------------------------------------------------
template<int SPLIT, int MODE>
__global__ __launch_bounds__(256, 3)
void gemm_bt(const u16* __restrict__ Ah, const u16* __restrict__ Al,
             const u16* __restrict__ Bh,
             const float* __restrict__ bias,
             float* __restrict__ Cf, u16* __restrict__ Ch, u16* __restrict__ Cl,
             int M, int N, int K,
             long batchA, long batchB, long batchC)
{
  extern __shared__ u16 smem[];
  u16* sAh = smem;                                   // BM*BK
  u16* sAl = (SPLIT == 2) ? (smem + BM * BK) : nullptr;
  u16* sBh = smem + (SPLIT == 2 ? 2 : 1) * BM * BK;  // BN*BK

  const int z = blockIdx.z;
  const u16* pAh = Ah + (size_t)z * batchA;
  const u16* pBh = Bh + (size_t)z * batchB;
  const u16* pAl = (SPLIT == 2) ? (Al + (size_t)z * batchA) : nullptr;

  const int tid = threadIdx.x;
  const int lane = tid & 63;
  const int wave = tid >> 6;
  const int wm = (wave >> 1) * 64;
  const int wn = (wave & 1) * 64;
  const int m0 = blockIdx.x * BM;
  const int n0 = blockIdx.y * BN;
  const int lr = lane & 15;   // frag row/col
  const int ls = lane >> 4;   // k-slot (8 elems each)

  f32x4 acc[4][4];
  const f32x4 zero4 = {0.f, 0.f, 0.f, 0.f};
#pragma unroll
  for (int i = 0; i < 4; ++i)
#pragma unroll
    for (int j = 0; j < 4; ++j)
      acc[i][j] = zero4;

  // staging coords: chunk c covers LDS bytes [c*16, c*16+16) = tile row c>>2,
  // 16B slot c&3.  Source column is slot XOR (row&3) -> LDS holds swizzled.
  const int c0 = tid, c1 = tid + 256;
  const int r0 = c0 >> 2, r1 = c1 >> 2;
  const int g0 = (((c0 & 3) ^ (r0 & 3)) << 3);
  const int g1 = (((c1 & 3) ^ (r1 & 3)) << 3);

  for (int kt = 0; kt < K; kt += BK) {
    size_t a0 = (size_t)(m0 + r0) * K + kt + g0;
    size_t a1 = (size_t)(m0 + r1) * K + kt + g1;
    size_t b0 = (size_t)(n0 + r0) * K + kt + g0;
    size_t b1 = (size_t)(n0 + r1) * K + kt + g1;
    gload_lds16(pAh + a0, sAh + c0 * 8);
    gload_lds16(pAh + a1, sAh + c1 * 8);
    gload_lds16(pBh + b0, sBh + c0 * 8);
    gload_lds16(pBh + b1, sBh + c1 * 8);
    if (SPLIT == 2) {
      gload_lds16(pAl + a0, sAl + c0 * 8);
      gload_lds16(pAl + a1, sAl + c1 * 8);
    }
    __syncthreads();   // compiler inserts vmcnt(0) drain before s_barrier

    f16x8 a_h[4], a_l[4];
#pragma unroll
    for (int mi = 0; mi < 4; ++mi) {
      int rr = wm + mi * 16 + lr;
      int off = rr * BK + ((ls ^ (rr & 3)) << 3);
      a_h[mi] = *(const f16x8*)(sAh + off);
      if (SPLIT == 2) a_l[mi] = *(const f16x8*)(sAl + off);
    }
#pragma unroll
    for (int ni = 0; ni < 4; ++ni) {
      int rr = wn + ni * 16 + lr;
      int off = rr * BK + ((ls ^ (rr & 3)) << 3);
      f16x8 b = *(const f16x8*)(sBh + off);
#pragma unroll
      for (int mi = 0; mi < 4; ++mi)
        acc[mi][ni] = __builtin_amdgcn_mfma_f32_16x16x32_f16(a_h[mi], b, acc[mi][ni], 0, 0, 0);
      if (SPLIT == 2) {
#pragma unroll
        for (int mi = 0; mi < 4; ++mi)
          acc[mi][ni] = __builtin_amdgcn_mfma_f32_16x16x32_f16(a_l[mi], b, acc[mi][ni], 0, 0, 0);
      }
    }
    __syncthreads();
  }

  // epilogue: C/D layout (verified m89/m91): col = lane&15, row = (lane>>4)*4 + r
#pragma unroll
  for (int mi = 0; mi < 4; ++mi) {
#pragma unroll
    for (int ni = 0; ni < 4; ++ni) {
#pragma unroll
      for (int r = 0; r < 4; ++r) {
        int row = m0 + wm + mi * 16 + ls * 4 + r;
        int col = n0 + wn + ni * 16 + lr;
        float v = acc[mi][ni][r];
        if (MODE == 0) {
          v += bias[col];
          u16 h = f32_to_f16(v);
          u16 l = f32_to_f16(v - f16_to_f32(h));
          size_t idx = (size_t)row * N + col;
          Ch[idx] = h;
          Cl[idx] = l;
        } else {
          Cf[(size_t)z * batchC + (size_t)row * N + col] = v;
        }
      }
    }
  }
}

// ---------------------------------------------------------------------------
// row softmax over Lk=2048, in place (fp32) + fp16 copy. 1 block (256t) / row.
// ---------------------------------------------------------------------------
__global__ __launch_bounds__(256)
void softmax_k(float* __restrict__ sc, u16* __restrict__ pf)
{
  __shared__ float redm[4], reds[4];
  size_t row = blockIdx.x;
  float* rp = sc + row * (size_t)LK;
  int tid = threadIdx.x;
  int lane = tid & 63, wv = tid >> 6;

  float4 v0 = *(const float4*)(rp + tid * 8);
  float4 v1 = *(const float4*)(rp + tid * 8 + 4);

  float m = fmaxf(fmaxf(fmaxf(v0.x, v0.y), fmaxf(v0.z, v0.w)),
                  fmaxf(fmaxf(v1.x, v1.y), fmaxf(v1.z, v1.w)));
#pragma unroll
  for (int off = 32; off > 0; off >>= 1)
    m = fmaxf(m, __shfl_xor(m, off));
  if (lane == 0) redm[wv] = m;
  __syncthreads();
  m = fmaxf(fmaxf(redm[0], redm[1]), fmaxf(redm[2], redm[3]));

  float e[8];
  e[0] = __expf(v0.x - m); e[1] = __expf(v0.y - m);
  e[2] = __expf(v0.z - m); e[3] = __expf(v0.w - m);
  e[4] = __expf(v1.x - m); e[5] = __expf(v1.y - m);
  e[6] = __expf(v1.z - m); e[7] = __expf(v1.w - m);
  float s = ((e[0] + e[1]) + (e[2] + e[3])) + ((e[4] + e[5]) + (e[6] + e[7]));
#pragma unroll
  for (int off = 32; off > 0; off >>= 1)
    s += __shfl_xor(s, off);
  if (lane == 0) reds[wv] = s;
  __syncthreads();
  s = (reds[0] + reds[1]) + (reds[2] + reds[3]);

  float inv = 1.0f / s;
  float4 p0 = {e[0] * inv, e[1] * inv, e[2] * inv, e[3] * inv};
  float4 p1 = {e[4] * inv, e[5] * inv, e[6] * inv, e[7] * inv};
  *(float4*)(rp + tid * 8) = p0;
  *(float4*)(rp + tid * 8 + 4) = p1;

  u16* pb = pf + row * (size_t)LK + tid * 8;
  ushort4 h0, h1;
  h0.x = f32_to_f16(p0.x); h0.y = f32_to_f16(p0.y);
  h0.z = f32_to_f16(p0.z); h0.w = f32_to_f16(p0.w);
  h1.x = f32_to_f16(p1.x); h1.y = f32_to_f16(p1.y);
  h1.z = f32_to_f16(p1.z); h1.w = f32_to_f16(p1.w);
  *(ushort4*)(pb) = h0;
  *(ushort4*)(pb + 4) = h1;
}

// ---------------------------------------------------------------------------
extern "C" void kernel_launch(void* const* d_in, const int* in_sizes, int n_in,
                              void* d_out, int out_size, void* d_ws, size_t ws_size,
                              hipStream_t stream)
{
  const float* q  = (const float*)d_in[0];
  const float* ky = (const float*)d_in[1];
  const float* vv = (const float*)d_in[2];
  const float* Ww = (const float*)d_in[3];
  const float* Wb = (const float*)d_in[4];
  float* out   = (float*)d_out;                       // [8,2048,1024]
  float* pattn = out + (size_t)B_SZ * LQ * HD;        // [8,2048,2048]

  char* ws = (char*)d_ws;
  const size_t SZ = (size_t)B_SZ * LQ * HD * 2;       // 33,554,432 B
  u16* qh  = (u16*)(ws);
  u16* ql  = (u16*)(ws + SZ);
  u16* kh  = (u16*)(ws + 2 * SZ);
  u16* vt  = (u16*)(ws + 3 * SZ);
  u16* wh  = (u16*)(ws + 4 * SZ);                     // 2 MB
  u16* qph = (u16*)(ws + 4 * SZ + 2097152);
  u16* qpl = (u16*)(ws + 5 * SZ + 2097152);
  u16* pf  = (u16*)(ws);   // reuses qh+ql region (dead after GEMM1) - 64 MB

  const int nq4 = (int)((size_t)B_SZ * LQ * HD / 4);  // 4,194,304
  const int nw4 = HD * HD / 4;                        // 262,144

  split_f16_k<<<2048, 256, 0, stream>>>((const float4*)q, (ushort4*)qh, (ushort4*)ql, nq4);
  cvt_f16_k<<<2048, 256, 0, stream>>>((const float4*)ky, (ushort4*)kh, nq4);
  cvt_f16_k<<<1024, 256, 0, stream>>>((const float4*)Ww, (ushort4*)wh, nw4);
  vtrans_k<<<dim3(HD / 32, LK / 32, B_SZ), dim3(32, 8), 0, stream>>>(vv, vt);

  // GEMM1: q_proj = q @ W^T + b  ->  fp16 hi/lo   (2-term: qh*W + ql*W)
  gemm_bt<2, 0><<<dim3(16384 / BM, HD / BN, 1), 256, 3 * BM * BK * 2, stream>>>(
      qh, ql, wh, Wb, nullptr, qph, qpl,
      B_SZ * LQ, HD, HD, 0, 0, 0);

  // GEMM2: scores = q_proj @ key^T -> fp32 straight into p_attn region
  gemm_bt<2, 1><<<dim3(LQ / BM, LK / BN, B_SZ), 256, 3 * BM * BK * 2, stream>>>(
      qph, qpl, kh, nullptr, pattn, nullptr, nullptr,
      LQ, LK, HD, (long)LQ * HD, (long)LK * HD, (long)LQ * LK);

  // softmax rows, in place + fp16 copy for PV
  softmax_k<<<B_SZ * LQ, 256, 0, stream>>>(pattn, pf);

  // GEMM3: out = p @ V   (Vt is [HD][LK] per batch -> B^T layout)
  gemm_bt<1, 1><<<dim3(LQ / BM, HD / BN, B_SZ), 256, 2 * BM * BK * 2, stream>>>(
      pf, nullptr, vt, nullptr, out, nullptr, nullptr,
      LQ, HD, LK, (long)LQ * LK, (long)HD * LK, (long)LQ * HD);
}

// Round 3
// 443.924 us; speedup vs baseline: 1.2068x; 1.0079x over previous
//
#include <hip/hip_runtime.h>

typedef unsigned short u16;
typedef _Float16 f16;
typedef f16 f16x8 __attribute__((ext_vector_type(8)));
typedef float f32x4 __attribute__((ext_vector_type(4)));

#define B_SZ 8
#define LQ 2048
#define LK 2048
#define HD 1024

#define BM 128
#define BN 128
#define BK 32

__device__ __forceinline__ u16 f32_to_f16(float x) {
  f16 h = (f16)x;
  return __builtin_bit_cast(u16, h);
}
__device__ __forceinline__ float f16_to_f32(u16 h) {
  return (float)__builtin_bit_cast(f16, h);
}

__device__ __forceinline__ void gload_lds16(const void* g, void* l) {
  __builtin_amdgcn_global_load_lds(
      (__attribute__((address_space(1))) void*)(g),
      (__attribute__((address_space(3))) void*)(l), 16, 0, 0);
}

// ---------------------------------------------------------------------------
// fp32 -> fp16 hi/lo split (elementwise, float4-vectorized)
// ---------------------------------------------------------------------------
__global__ __launch_bounds__(256)
void split_f16_k(const float4* __restrict__ x, ushort4* __restrict__ hi,
                 ushort4* __restrict__ lo, int n4)
{
  int i = blockIdx.x * blockDim.x + threadIdx.x;
  int stride = gridDim.x * blockDim.x;
  for (; i < n4; i += stride) {
    float4 f = x[i];
    ushort4 h, l;
    h.x = f32_to_f16(f.x); l.x = f32_to_f16(f.x - f16_to_f32(h.x));
    h.y = f32_to_f16(f.y); l.y = f32_to_f16(f.y - f16_to_f32(h.y));
    h.z = f32_to_f16(f.z); l.z = f32_to_f16(f.z - f16_to_f32(h.z));
    h.w = f32_to_f16(f.w); l.w = f32_to_f16(f.w - f16_to_f32(h.w));
    hi[i] = h; lo[i] = l;
  }
}

// fp32 -> fp16 single
__global__ __launch_bounds__(256)
void cvt_f16_k(const float4* __restrict__ x, ushort4* __restrict__ o, int n4)
{
  int i = blockIdx.x * blockDim.x + threadIdx.x;
  int stride = gridDim.x * blockDim.x;
  for (; i < n4; i += stride) {
    float4 f = x[i];
    ushort4 h;
    h.x = f32_to_f16(f.x); h.y = f32_to_f16(f.y);
    h.z = f32_to_f16(f.z); h.w = f32_to_f16(f.w);
    o[i] = h;
  }
}

// ---------------------------------------------------------------------------
// V [B][LK][HD] fp32 -> Vt [B][HD][LK] fp16 (32x32 LDS tile transpose)
// ---------------------------------------------------------------------------
__global__ __launch_bounds__(256)
void vtrans_k(const float* __restrict__ V, u16* __restrict__ Vt)
{
  __shared__ float t[32][33];
  int z = blockIdx.z;
  int tx = threadIdx.x, ty = threadIdx.y;
  int h0 = blockIdx.x * 32, k0 = blockIdx.y * 32;
  const float* Vb = V + (size_t)z * LK * HD;
  u16* Vtb = Vt + (size_t)z * HD * LK;
#pragma unroll
  for (int i = 0; i < 4; ++i)
    t[ty + i * 8][tx] = Vb[(size_t)(k0 + ty + i * 8) * HD + h0 + tx];
  __syncthreads();
#pragma unroll
  for (int i = 0; i < 4; ++i)
    Vtb[(size_t)(h0 + ty + i * 8) * LK + k0 + tx] = f32_to_f16(t[tx][ty + i * 8]);
}

// ---------------------------------------------------------------------------
// B^T-layout GEMM, 2-deep counted-vmcnt pipeline (T3/T4/T5 on 128^2 tile).
//   C[m,n] = sum_k A[m,k] * Bt[n,k]   (fp16 MFMA)
//   SPLIT==2: C = Ah*B + Al*B ; SPLIT==1: C = Ah*B
//   MODE==0:  C += bias[n]; store fp16 hi/lo into Ch/Cl
//   MODE==1:  store fp32 into Cf
// Schedule per K-step t:
//   ds_read frags(buf[t&1]) ; lgkmcnt(0)+sched_barrier ; s_barrier
//   stage(buf[t&1], t+2)    ; setprio(1) MFMA setprio(0)
//   vmcnt(LOADS)  [counted — t+2's loads stay in flight] ; s_barrier
// Race-free: overwrite issued only after the all-read barrier; t+1
// readiness = per-wave counted vmcnt + joining barrier.
// ---------------------------------------------------------------------------
template<int SPLIT, int MODE>
__global__ __launch_bounds__(256, 3)
void gemm_bt(const u16* __restrict__ Ah, const u16* __restrict__ Al,
             const u16* __restrict__ Bh,
             const float* __restrict__ bias,
             float* __restrict__ Cf, u16* __restrict__ Ch, u16* __restrict__ Cl,
             int M, int N, int K,
             long batchA, long batchB, long batchC)
{
  constexpr int NARR = (SPLIT == 2) ? 3 : 2;   // Ah [, Al], B
  constexpr int ASZ = BM * BK;                  // u16 elements per array
  extern __shared__ u16 smem[];                 // 2 * NARR * ASZ

  const int z = blockIdx.z;
  const u16* pAh = Ah + (size_t)z * batchA;
  const u16* pBh = Bh + (size_t)z * batchB;
  const u16* pAl = (SPLIT == 2) ? (Al + (size_t)z * batchA) : nullptr;

  const int tid = threadIdx.x;
  const int lane = tid & 63;
  const int wave = tid >> 6;
  const int wm = (wave >> 1) * 64;
  const int wn = (wave & 1) * 64;
  const int m0 = blockIdx.x * BM;
  const int n0 = blockIdx.y * BN;
  const int lr = lane & 15;   // frag row/col
  const int ls = lane >> 4;   // k-slot (8 elems each)

  f32x4 acc[4][4];
  const f32x4 zero4 = {0.f, 0.f, 0.f, 0.f};
#pragma unroll
  for (int i = 0; i < 4; ++i)
#pragma unroll
    for (int j = 0; j < 4; ++j)
      acc[i][j] = zero4;

  // staging coords: chunk c covers LDS bytes [c*16, c*16+16) = tile row c>>2,
  // 16B slot c&3.  Source slot is (c&3) XOR (row&3) -> LDS holds swizzled
  // rows; undone on the ds_read side. Conflict-free b128 reads.
  const int c0 = tid, c1 = tid + 256;
  const int r0 = c0 >> 2, r1 = c1 >> 2;
  const int g0 = (((c0 & 3) ^ (r0 & 3)) << 3);
  const int g1 = (((c1 & 3) ^ (r1 & 3)) << 3);

  // per-fragment LDS element offsets (read side, swizzle undone)
  int offA[4], offB[4];
#pragma unroll
  for (int mi = 0; mi < 4; ++mi) {
    int rr = wm + mi * 16 + lr;
    offA[mi] = rr * BK + ((ls ^ (rr & 3)) << 3);
  }
#pragma unroll
  for (int ni = 0; ni < 4; ++ni) {
    int rr = wn + ni * 16 + lr;
    offB[ni] = rr * BK + ((ls ^ (rr & 3)) << 3);
  }

  auto stage = [&](int bufsel, int t) {
    u16* b = smem + bufsel * (NARR * ASZ);
    size_t kt = (size_t)t * BK;
    size_t a0 = (size_t)(m0 + r0) * K + kt + g0;
    size_t a1 = (size_t)(m0 + r1) * K + kt + g1;
    size_t b0 = (size_t)(n0 + r0) * K + kt + g0;
    size_t b1 = (size_t)(n0 + r1) * K + kt + g1;
    gload_lds16(pAh + a0, b + c0 * 8);
    gload_lds16(pAh + a1, b + c1 * 8);
    if (SPLIT == 2) {
      gload_lds16(pAl + a0, b + ASZ + c0 * 8);
      gload_lds16(pAl + a1, b + ASZ + c1 * 8);
    }
    gload_lds16(pBh + b0, b + (NARR - 1) * ASZ + c0 * 8);
    gload_lds16(pBh + b1, b + (NARR - 1) * ASZ + c1 * 8);
  };

  const int T = K / BK;
  stage(0, 0);
  stage(1, 1);
  // wait tile 0 only; tile 1's loads remain in flight
  if constexpr (SPLIT == 2) asm volatile("s_waitcnt vmcnt(6)" ::: "memory");
  else                      asm volatile("s_waitcnt vmcnt(4)" ::: "memory");
  __builtin_amdgcn_s_barrier();

  for (int t = 0; t < T; ++t) {
    u16* cb = smem + (t & 1) * (NARR * ASZ);

    f16x8 a_h[4], a_l[4], bf[4];
#pragma unroll
    for (int mi = 0; mi < 4; ++mi) {
      a_h[mi] = *(const f16x8*)(cb + offA[mi]);
      if (SPLIT == 2) a_l[mi] = *(const f16x8*)(cb + ASZ + offA[mi]);
    }
#pragma unroll
    for (int ni = 0; ni < 4; ++ni)
      bf[ni] = *(const f16x8*)(cb + (NARR - 1) * ASZ + offB[ni]);

    // all frags in regs before the barrier (so t+2 stage may overwrite)
    asm volatile("s_waitcnt lgkmcnt(0)" ::: "memory");
    __builtin_amdgcn_sched_barrier(0);
    __builtin_amdgcn_s_barrier();

    if (t + 2 < T) stage(t & 1, t + 2);
    __builtin_amdgcn_sched_barrier(0);

    __builtin_amdgcn_s_setprio(1);
#pragma unroll
    for (int ni = 0; ni < 4; ++ni) {
#pragma unroll
      for (int mi = 0; mi < 4; ++mi)
        acc[mi][ni] = __builtin_amdgcn_mfma_f32_16x16x32_f16(a_h[mi], bf[ni], acc[mi][ni], 0, 0, 0);
      if (SPLIT == 2) {
#pragma unroll
        for (int mi = 0; mi < 4; ++mi)
          acc[mi][ni] = __builtin_amdgcn_mfma_f32_16x16x32_f16(a_l[mi], bf[ni], acc[mi][ni], 0, 0, 0);
      }
    }
    __builtin_amdgcn_s_setprio(0);
    __builtin_amdgcn_sched_barrier(0);

    if (t + 1 < T) {
      if (t + 2 < T) {
        // counted: wait tile t+1 landed; tile t+2's loads stay in flight
        if constexpr (SPLIT == 2) asm volatile("s_waitcnt vmcnt(6)" ::: "memory");
        else                      asm volatile("s_waitcnt vmcnt(4)" ::: "memory");
      } else {
        asm volatile("s_waitcnt vmcnt(0)" ::: "memory");
      }
      __builtin_amdgcn_s_barrier();
    }
  }

  // epilogue: C/D layout: col = lane&15, row = (lane>>4)*4 + r
#pragma unroll
  for (int mi = 0; mi < 4; ++mi) {
#pragma unroll
    for (int ni = 0; ni < 4; ++ni) {
#pragma unroll
      for (int r = 0; r < 4; ++r) {
        int row = m0 + wm + mi * 16 + ls * 4 + r;
        int col = n0 + wn + ni * 16 + lr;
        float v = acc[mi][ni][r];
        if (MODE == 0) {
          v += bias[col];
          u16 h = f32_to_f16(v);
          u16 l = f32_to_f16(v - f16_to_f32(h));
          size_t idx = (size_t)row * N + col;
          Ch[idx] = h;
          Cl[idx] = l;
        } else {
          Cf[(size_t)z * batchC + (size_t)row * N + col] = v;
        }
      }
    }
  }
}

// ---------------------------------------------------------------------------
// row softmax over Lk=2048, in place (fp32) + fp16 copy. 1 block (256t) / row.
// ---------------------------------------------------------------------------
__global__ __launch_bounds__(256)
void softmax_k(float* __restrict__ sc, u16* __restrict__ pf)
{
  __shared__ float redm[4], reds[4];
  size_t row = blockIdx.x;
  float* rp = sc + row * (size_t)LK;
  int tid = threadIdx.x;
  int lane = tid & 63, wv = tid >> 6;

  float4 v0 = *(const float4*)(rp + tid * 8);
  float4 v1 = *(const float4*)(rp + tid * 8 + 4);

  float m = fmaxf(fmaxf(fmaxf(v0.x, v0.y), fmaxf(v0.z, v0.w)),
                  fmaxf(fmaxf(v1.x, v1.y), fmaxf(v1.z, v1.w)));
#pragma unroll
  for (int off = 32; off > 0; off >>= 1)
    m = fmaxf(m, __shfl_xor(m, off));
  if (lane == 0) redm[wv] = m;
  __syncthreads();
  m = fmaxf(fmaxf(redm[0], redm[1]), fmaxf(redm[2], redm[3]));

  float e[8];
  e[0] = __expf(v0.x - m); e[1] = __expf(v0.y - m);
  e[2] = __expf(v0.z - m); e[3] = __expf(v0.w - m);
  e[4] = __expf(v1.x - m); e[5] = __expf(v1.y - m);
  e[6] = __expf(v1.z - m); e[7] = __expf(v1.w - m);
  float s = ((e[0] + e[1]) + (e[2] + e[3])) + ((e[4] + e[5]) + (e[6] + e[7]));
#pragma unroll
  for (int off = 32; off > 0; off >>= 1)
    s += __shfl_xor(s, off);
  if (lane == 0) reds[wv] = s;
  __syncthreads();
  s = (reds[0] + reds[1]) + (reds[2] + reds[3]);

  float inv = 1.0f / s;
  float4 p0 = {e[0] * inv, e[1] * inv, e[2] * inv, e[3] * inv};
  float4 p1 = {e[4] * inv, e[5] * inv, e[6] * inv, e[7] * inv};
  *(float4*)(rp + tid * 8) = p0;
  *(float4*)(rp + tid * 8 + 4) = p1;

  u16* pb = pf + row * (size_t)LK + tid * 8;
  ushort4 h0, h1;
  h0.x = f32_to_f16(p0.x); h0.y = f32_to_f16(p0.y);
  h0.z = f32_to_f16(p0.z); h0.w = f32_to_f16(p0.w);
  h1.x = f32_to_f16(p1.x); h1.y = f32_to_f16(p1.y);
  h1.z = f32_to_f16(p1.z); h1.w = f32_to_f16(p1.w);
  *(ushort4*)(pb) = h0;
  *(ushort4*)(pb + 4) = h1;
}

// ---------------------------------------------------------------------------
extern "C" void kernel_launch(void* const* d_in, const int* in_sizes, int n_in,
                              void* d_out, int out_size, void* d_ws, size_t ws_size,
                              hipStream_t stream)
{
  const float* q  = (const float*)d_in[0];
  const float* ky = (const float*)d_in[1];
  const float* vv = (const float*)d_in[2];
  const float* Ww = (const float*)d_in[3];
  const float* Wb = (const float*)d_in[4];
  float* out   = (float*)d_out;                       // [8,2048,1024]
  float* pattn = out + (size_t)B_SZ * LQ * HD;        // [8,2048,2048]

  char* ws = (char*)d_ws;
  const size_t SZ = (size_t)B_SZ * LQ * HD * 2;       // 33,554,432 B
  u16* qh  = (u16*)(ws);
  u16* ql  = (u16*)(ws + SZ);
  u16* kh  = (u16*)(ws + 2 * SZ);
  u16* vt  = (u16*)(ws + 3 * SZ);
  u16* wh  = (u16*)(ws + 4 * SZ);                     // 2 MB
  u16* qph = (u16*)(ws + 4 * SZ + 2097152);
  u16* qpl = (u16*)(ws + 5 * SZ + 2097152);
  u16* pf  = (u16*)(ws);   // reuses qh+ql region (dead after GEMM1) - 64 MB

  const int nq4 = (int)((size_t)B_SZ * LQ * HD / 4);  // 4,194,304
  const int nw4 = HD * HD / 4;                        // 262,144

  split_f16_k<<<2048, 256, 0, stream>>>((const float4*)q, (ushort4*)qh, (ushort4*)ql, nq4);
  cvt_f16_k<<<2048, 256, 0, stream>>>((const float4*)ky, (ushort4*)kh, nq4);
  cvt_f16_k<<<1024, 256, 0, stream>>>((const float4*)Ww, (ushort4*)wh, nw4);
  vtrans_k<<<dim3(HD / 32, LK / 32, B_SZ), dim3(32, 8), 0, stream>>>(vv, vt);

  // GEMM1: q_proj = q @ W^T + b  ->  fp16 hi/lo   (2-term: qh*W + ql*W)
  gemm_bt<2, 0><<<dim3(16384 / BM, HD / BN, 1), 256, 2 * 3 * BM * BK * 2, stream>>>(
      qh, ql, wh, Wb, nullptr, qph, qpl,
      B_SZ * LQ, HD, HD, 0, 0, 0);

  // GEMM2: scores = q_proj @ key^T -> fp32 straight into p_attn region
  gemm_bt<2, 1><<<dim3(LQ / BM, LK / BN, B_SZ), 256, 2 * 3 * BM * BK * 2, stream>>>(
      qph, qpl, kh, nullptr, pattn, nullptr, nullptr,
      LQ, LK, HD, (long)LQ * HD, (long)LK * HD, (long)LQ * LK);

  // softmax rows, in place + fp16 copy for PV
  softmax_k<<<B_SZ * LQ, 256, 0, stream>>>(pattn, pf);

  // GEMM3: out = p @ V   (Vt is [HD][LK] per batch -> B^T layout)
  gemm_bt<1, 1><<<dim3(LQ / BM, HD / BN, B_SZ), 256, 2 * 2 * BM * BK * 2, stream>>>(
      pf, nullptr, vt, nullptr, out, nullptr, nullptr,
      LQ, HD, LK, (long)LQ * LK, (long)HD * LK, (long)LQ * HD);
}

// Round 4
// 405.663 us; speedup vs baseline: 1.3206x; 1.0943x over previous
//
#include <hip/hip_runtime.h>

typedef unsigned short u16;
typedef _Float16 f16;
typedef f16 f16x8 __attribute__((ext_vector_type(8)));
typedef float f32x4 __attribute__((ext_vector_type(4)));

#define B_SZ 8
#define LQ 2048
#define LK 2048
#define HD 1024

__device__ __forceinline__ u16 f32_to_f16(float x) {
  f16 h = (f16)x;
  return __builtin_bit_cast(u16, h);
}
__device__ __forceinline__ float f16_to_f32(u16 h) {
  return (float)__builtin_bit_cast(f16, h);
}

__device__ __forceinline__ void gload_lds16(const void* g, void* l) {
  __builtin_amdgcn_global_load_lds(
      (__attribute__((address_space(1))) void*)(g),
      (__attribute__((address_space(3))) void*)(l), 16, 0, 0);
}

// ---------------------------------------------------------------------------
// q [16384][1024] fp32 -> q' [16384][2048] fp16, hi at [m][k], lo at [m][1024+k]
// ---------------------------------------------------------------------------
__global__ __launch_bounds__(256)
void split_concat_k(const float4* __restrict__ x, u16* __restrict__ o, int n4)
{
  int i = blockIdx.x * blockDim.x + threadIdx.x;
  int stride = gridDim.x * blockDim.x;
  for (; i < n4; i += stride) {
    float4 f = x[i];
    int row = i >> 8;            // 256 float4 per 1024-col row
    int c = (i & 255) << 2;
    ushort4 h, l;
    h.x = f32_to_f16(f.x); l.x = f32_to_f16(f.x - f16_to_f32(h.x));
    h.y = f32_to_f16(f.y); l.y = f32_to_f16(f.y - f16_to_f32(h.y));
    h.z = f32_to_f16(f.z); l.z = f32_to_f16(f.z - f16_to_f32(h.z));
    h.w = f32_to_f16(f.w); l.w = f32_to_f16(f.w - f16_to_f32(h.w));
    *(ushort4*)(o + (size_t)row * 2048 + c) = h;
    *(ushort4*)(o + (size_t)row * 2048 + 1024 + c) = l;
  }
}

// fp32 -> fp16 single
__global__ __launch_bounds__(256)
void cvt_f16_k(const float4* __restrict__ x, ushort4* __restrict__ o, int n4)
{
  int i = blockIdx.x * blockDim.x + threadIdx.x;
  int stride = gridDim.x * blockDim.x;
  for (; i < n4; i += stride) {
    float4 f = x[i];
    ushort4 h;
    h.x = f32_to_f16(f.x); h.y = f32_to_f16(f.y);
    h.z = f32_to_f16(f.z); h.w = f32_to_f16(f.w);
    o[i] = h;
  }
}

// ---------------------------------------------------------------------------
// V [B][LK][HD] fp32 -> Vt [B][HD][LK] fp16 (32x32 LDS tile transpose)
// ---------------------------------------------------------------------------
__global__ __launch_bounds__(256)
void vtrans_k(const float* __restrict__ V, u16* __restrict__ Vt)
{
  __shared__ float t[32][33];
  int z = blockIdx.z;
  int tx = threadIdx.x, ty = threadIdx.y;
  int h0 = blockIdx.x * 32, k0 = blockIdx.y * 32;
  const float* Vb = V + (size_t)z * LK * HD;
  u16* Vtb = Vt + (size_t)z * HD * LK;
#pragma unroll
  for (int i = 0; i < 4; ++i)
    t[ty + i * 8][tx] = Vb[(size_t)(k0 + ty + i * 8) * HD + h0 + tx];
  __syncthreads();
#pragma unroll
  for (int i = 0; i < 4; ++i)
    Vtb[(size_t)(h0 + ty + i * 8) * LK + k0 + tx] = f32_to_f16(t[tx][ty + i * 8]);
}

// ---------------------------------------------------------------------------
// 256x256 B^T GEMM, K=2048 (T=64 tiles of BK=32), quad-buffered LDS (128 KB),
// counted vmcnt(8) pipeline, 8 waves (2M x 4N), per-wave 128x64 output.
//   C[m,n] = sum_k A[m,k] * Bt[n,k]   (fp16 MFMA, fp32 acc)
//   B source k is masked by KB-1 (KB=1024 -> tiles 32..63 re-read B; pairs
//   with A's hi|lo K-concat layout to give the 2-term split product).
//   MODE==0: C += bias[n]; split into fp16 hi/lo, stored K-concat in Ch.
//   MODE==1: store fp32 into Cf.
// Race analysis: iter t stages tile t+3 into buf[(t+3)&3] = buf[(t-1)&3],
// whose reads drained (lgkmcnt(0)) before iter t-1's end barrier. End-of-iter
// vmcnt(8) leaves tiles t+2,t+3 (4 loads each) in flight; tile t+1 is landed
// before any wave passes the barrier. Epilogue drains 8->4->0.
// LDS swizzle: stored slot = s ^ ((row>>1)&3) (involution, applied on the
// global SOURCE, linear LDS dest, undone on ds_read). 16 lanes at 64B row
// stride then cover the 128B bank space exactly twice -> 2-way (free).
// ---------------------------------------------------------------------------
template<int MODE>
__global__ __launch_bounds__(512, 2)
void gemm256(const u16* __restrict__ A, const u16* __restrict__ Bt,
             const float* __restrict__ bias,
             float* __restrict__ Cf, u16* __restrict__ Ch,
             int N, int KB, long batchA, long batchB, long batchC)
{
  constexpr int KA = 2048;
  extern __shared__ u16 smem[];   // 4 bufs x (8192 A + 8192 B) u16 = 128 KB

  const int z = blockIdx.z;
  const u16* pA = A + (size_t)z * batchA;
  const u16* pB = Bt + (size_t)z * batchB;
  const int kmask = KB - 1;

  const int tid = threadIdx.x;
  const int lane = tid & 63;
  const int wave = tid >> 6;      // 0..7
  const int wr = wave >> 2;       // 0..1  (M)
  const int wc = wave & 3;        // 0..3  (N)
  const int m0 = blockIdx.x * 256;
  const int n0 = blockIdx.y * 256;
  const int lr = lane & 15;
  const int ls = lane >> 4;

  // staging chunk coords: chunk c = 16B at LDS offset c*16; row=c>>2, slot=c&3
  const int c0 = tid, c1 = tid + 512;
  const int r0 = c0 >> 2, s0 = c0 & 3;
  const int r1 = c1 >> 2, s1 = c1 & 3;
  const int ga0 = ((s0 ^ ((r0 >> 1) & 3)) << 3);
  const int ga1 = ((s1 ^ ((r1 >> 1) & 3)) << 3);

  f32x4 acc[8][4];
  const f32x4 zero4 = {0.f, 0.f, 0.f, 0.f};
#pragma unroll
  for (int i = 0; i < 8; ++i)
#pragma unroll
    for (int j = 0; j < 4; ++j)
      acc[i][j] = zero4;

  int offA[8], offB[4];
#pragma unroll
  for (int mi = 0; mi < 8; ++mi) {
    int rr = wr * 128 + mi * 16 + lr;
    offA[mi] = rr * 32 + ((ls ^ ((rr >> 1) & 3)) << 3);
  }
#pragma unroll
  for (int ni = 0; ni < 4; ++ni) {
    int rr = wc * 64 + ni * 16 + lr;
    offB[ni] = 8192 + rr * 32 + ((ls ^ ((rr >> 1) & 3)) << 3);
  }

  auto stage = [&](int t) {
    u16* b = smem + (t & 3) * 16384;
    int kt = t * 32;
    int ktb = kt & kmask;
    gload_lds16(pA + (size_t)(m0 + r0) * KA + kt + ga0, b + c0 * 8);
    gload_lds16(pA + (size_t)(m0 + r1) * KA + kt + ga1, b + c1 * 8);
    gload_lds16(pB + (size_t)(n0 + r0) * KB + ktb + ga0, b + 8192 + c0 * 8);
    gload_lds16(pB + (size_t)(n0 + r1) * KB + ktb + ga1, b + 8192 + c1 * 8);
  };

  auto body = [&](int t) {
    const u16* cb = smem + (t & 3) * 16384;
    f16x8 bfr[4], afr[8];
#pragma unroll
    for (int ni = 0; ni < 4; ++ni)
      bfr[ni] = *(const f16x8*)(cb + offB[ni]);
#pragma unroll
    for (int mi = 0; mi < 8; ++mi)
      afr[mi] = *(const f16x8*)(cb + offA[mi]);
    __builtin_amdgcn_s_setprio(1);
#pragma unroll
    for (int ni = 0; ni < 4; ++ni)
#pragma unroll
      for (int mi = 0; mi < 8; ++mi)
        acc[mi][ni] = __builtin_amdgcn_mfma_f32_16x16x32_f16(afr[mi], bfr[ni], acc[mi][ni], 0, 0, 0);
    __builtin_amdgcn_s_setprio(0);
  };

  // prologue: 3 tiles in flight, wait tile 0 (12 loads out, keep 8)
  stage(0); stage(1); stage(2);
  asm volatile("s_waitcnt vmcnt(8)" ::: "memory");
  __builtin_amdgcn_s_barrier();
  __builtin_amdgcn_sched_barrier(0);

  for (int t = 0; t < 61; ++t) {
    stage(t + 3);
    body(t);
    asm volatile("s_waitcnt vmcnt(8) lgkmcnt(0)" ::: "memory");
    __builtin_amdgcn_sched_barrier(0);
    __builtin_amdgcn_s_barrier();
    __builtin_amdgcn_sched_barrier(0);
  }
  body(61);
  asm volatile("s_waitcnt vmcnt(4) lgkmcnt(0)" ::: "memory");
  __builtin_amdgcn_sched_barrier(0);
  __builtin_amdgcn_s_barrier();
  __builtin_amdgcn_sched_barrier(0);
  body(62);
  asm volatile("s_waitcnt vmcnt(0) lgkmcnt(0)" ::: "memory");
  __builtin_amdgcn_sched_barrier(0);
  __builtin_amdgcn_s_barrier();
  __builtin_amdgcn_sched_barrier(0);
  body(63);

  // epilogue: C/D layout: col = lane&15 (lr), row = ls*4 + r within frag
#pragma unroll
  for (int mi = 0; mi < 8; ++mi) {
#pragma unroll
    for (int ni = 0; ni < 4; ++ni) {
#pragma unroll
      for (int r = 0; r < 4; ++r) {
        int row = m0 + wr * 128 + mi * 16 + ls * 4 + r;
        int col = n0 + wc * 64 + ni * 16 + lr;
        float v = acc[mi][ni][r];
        if (MODE == 0) {
          v += bias[col];
          u16 h = f32_to_f16(v);
          u16 l = f32_to_f16(v - f16_to_f32(h));
          Ch[(size_t)row * (2 * N) + col] = h;
          Ch[(size_t)row * (2 * N) + N + col] = l;
        } else {
          Cf[(size_t)z * batchC + (size_t)row * N + col] = v;
        }
      }
    }
  }
}

// ---------------------------------------------------------------------------
// row softmax over Lk=2048, in place (fp32) + fp16 copy. 1 block (256t) / row.
// ---------------------------------------------------------------------------
__global__ __launch_bounds__(256)
void softmax_k(float* __restrict__ sc, u16* __restrict__ pf)
{
  __shared__ float redm[4], reds[4];
  size_t row = blockIdx.x;
  float* rp = sc + row * (size_t)LK;
  int tid = threadIdx.x;
  int lane = tid & 63, wv = tid >> 6;

  float4 v0 = *(const float4*)(rp + tid * 8);
  float4 v1 = *(const float4*)(rp + tid * 8 + 4);

  float m = fmaxf(fmaxf(fmaxf(v0.x, v0.y), fmaxf(v0.z, v0.w)),
                  fmaxf(fmaxf(v1.x, v1.y), fmaxf(v1.z, v1.w)));
#pragma unroll
  for (int off = 32; off > 0; off >>= 1)
    m = fmaxf(m, __shfl_xor(m, off));
  if (lane == 0) redm[wv] = m;
  __syncthreads();
  m = fmaxf(fmaxf(redm[0], redm[1]), fmaxf(redm[2], redm[3]));

  float e[8];
  e[0] = __expf(v0.x - m); e[1] = __expf(v0.y - m);
  e[2] = __expf(v0.z - m); e[3] = __expf(v0.w - m);
  e[4] = __expf(v1.x - m); e[5] = __expf(v1.y - m);
  e[6] = __expf(v1.z - m); e[7] = __expf(v1.w - m);
  float s = ((e[0] + e[1]) + (e[2] + e[3])) + ((e[4] + e[5]) + (e[6] + e[7]));
#pragma unroll
  for (int off = 32; off > 0; off >>= 1)
    s += __shfl_xor(s, off);
  if (lane == 0) reds[wv] = s;
  __syncthreads();
  s = (reds[0] + reds[1]) + (reds[2] + reds[3]);

  float inv = 1.0f / s;
  float4 p0 = {e[0] * inv, e[1] * inv, e[2] * inv, e[3] * inv};
  float4 p1 = {e[4] * inv, e[5] * inv, e[6] * inv, e[7] * inv};
  *(float4*)(rp + tid * 8) = p0;
  *(float4*)(rp + tid * 8 + 4) = p1;

  u16* pb = pf + row * (size_t)LK + tid * 8;
  ushort4 h0, h1;
  h0.x = f32_to_f16(p0.x); h0.y = f32_to_f16(p0.y);
  h0.z = f32_to_f16(p0.z); h0.w = f32_to_f16(p0.w);
  h1.x = f32_to_f16(p1.x); h1.y = f32_to_f16(p1.y);
  h1.z = f32_to_f16(p1.z); h1.w = f32_to_f16(p1.w);
  *(ushort4*)(pb) = h0;
  *(ushort4*)(pb + 4) = h1;
}

// ---------------------------------------------------------------------------
extern "C" void kernel_launch(void* const* d_in, const int* in_sizes, int n_in,
                              void* d_out, int out_size, void* d_ws, size_t ws_size,
                              hipStream_t stream)
{
  const float* q  = (const float*)d_in[0];
  const float* ky = (const float*)d_in[1];
  const float* vv = (const float*)d_in[2];
  const float* Ww = (const float*)d_in[3];
  const float* Wb = (const float*)d_in[4];
  float* out   = (float*)d_out;                       // [8,2048,1024]
  float* pattn = out + (size_t)B_SZ * LQ * HD;        // [8,2048,2048]

  char* ws = (char*)d_ws;
  u16* qs = (u16*)(ws);                               // q split-concat, 64 MB
  u16* kh = (u16*)(ws + 67108864);                    // key fp16, 32 MB
  u16* wh = (u16*)(ws + 100663296);                   // W fp16, 2 MB
  u16* vt = (u16*)(ws + 102760448);                   // V^T fp16, 32 MB
  u16* qp = (u16*)(ws + 136314880);                   // q_proj split-concat, 64 MB
  u16* pf = (u16*)(ws);                               // p fp16 (reuses qs)

  const int nq4 = (int)((size_t)B_SZ * LQ * HD / 4);  // 4,194,304
  const int nw4 = HD * HD / 4;                        // 262,144

  split_concat_k<<<2048, 256, 0, stream>>>((const float4*)q, qs, nq4);
  cvt_f16_k<<<2048, 256, 0, stream>>>((const float4*)ky, (ushort4*)kh, nq4);
  cvt_f16_k<<<1024, 256, 0, stream>>>((const float4*)Ww, (ushort4*)wh, nw4);
  vtrans_k<<<dim3(HD / 32, LK / 32, B_SZ), dim3(32, 8), 0, stream>>>(vv, vt);

  // GEMM1: q_proj = q @ W^T + b  (A = [qh|ql] K-concat, B masked k&1023)
  gemm256<0><<<dim3(64, 4, 1), 512, 131072, stream>>>(
      qs, wh, Wb, nullptr, qp,
      HD, HD, 0, 0, 0);

  // GEMM2: scores = q_proj @ key^T -> fp32 into p_attn region
  gemm256<1><<<dim3(8, 8, 8), 512, 131072, stream>>>(
      qp, kh, nullptr, pattn, nullptr,
      LK, HD, (long)LQ * 2 * HD, (long)LK * HD, (long)LQ * LK);

  // softmax rows, in place + fp16 copy for PV
  softmax_k<<<B_SZ * LQ, 256, 0, stream>>>(pattn, pf);

  // GEMM3: out = p @ V   (Vt is [HD][LK] per batch, KB=2048 -> mask no-op)
  gemm256<1><<<dim3(8, 4, 8), 512, 131072, stream>>>(
      pf, vt, nullptr, out, nullptr,
      HD, LK, (long)LQ * LK, (long)HD * LK, (long)LQ * HD);
}

// Round 5
// 404.205 us; speedup vs baseline: 1.3254x; 1.0036x over previous
//
#include <hip/hip_runtime.h>

typedef unsigned short u16;
typedef _Float16 f16;
typedef f16 f16x8 __attribute__((ext_vector_type(8)));
typedef float f32x4 __attribute__((ext_vector_type(4)));

#define B_SZ 8
#define LQ 2048
#define LK 2048
#define HD 1024

__device__ __forceinline__ u16 f32_to_f16(float x) {
  f16 h = (f16)x;
  return __builtin_bit_cast(u16, h);
}
__device__ __forceinline__ float f16_to_f32(u16 h) {
  return (float)__builtin_bit_cast(f16, h);
}

__device__ __forceinline__ void gload_lds16(const void* g, void* l) {
  __builtin_amdgcn_global_load_lds(
      (__attribute__((address_space(1))) void*)(g),
      (__attribute__((address_space(3))) void*)(l), 16, 0, 0);
}

// ---------------------------------------------------------------------------
// q [16384][1024] fp32 -> q' [16384][2048] fp16, hi at [m][k], lo at [m][1024+k]
// ---------------------------------------------------------------------------
__global__ __launch_bounds__(256)
void split_concat_k(const float4* __restrict__ x, u16* __restrict__ o, int n4)
{
  int i = blockIdx.x * blockDim.x + threadIdx.x;
  int stride = gridDim.x * blockDim.x;
  for (; i < n4; i += stride) {
    float4 f = x[i];
    int row = i >> 8;            // 256 float4 per 1024-col row
    int c = (i & 255) << 2;
    ushort4 h, l;
    h.x = f32_to_f16(f.x); l.x = f32_to_f16(f.x - f16_to_f32(h.x));
    h.y = f32_to_f16(f.y); l.y = f32_to_f16(f.y - f16_to_f32(h.y));
    h.z = f32_to_f16(f.z); l.z = f32_to_f16(f.z - f16_to_f32(h.z));
    h.w = f32_to_f16(f.w); l.w = f32_to_f16(f.w - f16_to_f32(h.w));
    *(ushort4*)(o + (size_t)row * 2048 + c) = h;
    *(ushort4*)(o + (size_t)row * 2048 + 1024 + c) = l;
  }
}

// fp32 -> fp16 single
__global__ __launch_bounds__(256)
void cvt_f16_k(const float4* __restrict__ x, ushort4* __restrict__ o, int n4)
{
  int i = blockIdx.x * blockDim.x + threadIdx.x;
  int stride = gridDim.x * blockDim.x;
  for (; i < n4; i += stride) {
    float4 f = x[i];
    ushort4 h;
    h.x = f32_to_f16(f.x); h.y = f32_to_f16(f.y);
    h.z = f32_to_f16(f.z); h.w = f32_to_f16(f.w);
    o[i] = h;
  }
}

// ---------------------------------------------------------------------------
// V [B][LK][HD] fp32 -> Vt [B][HD][LK] fp16 (32x32 LDS tile transpose)
// ---------------------------------------------------------------------------
__global__ __launch_bounds__(256)
void vtrans_k(const float* __restrict__ V, u16* __restrict__ Vt)
{
  __shared__ float t[32][33];
  int z = blockIdx.z;
  int tx = threadIdx.x, ty = threadIdx.y;
  int h0 = blockIdx.x * 32, k0 = blockIdx.y * 32;
  const float* Vb = V + (size_t)z * LK * HD;
  u16* Vtb = Vt + (size_t)z * HD * LK;
#pragma unroll
  for (int i = 0; i < 4; ++i)
    t[ty + i * 8][tx] = Vb[(size_t)(k0 + ty + i * 8) * HD + h0 + tx];
  __syncthreads();
#pragma unroll
  for (int i = 0; i < 4; ++i)
    Vtb[(size_t)(h0 + ty + i * 8) * LK + k0 + tx] = f32_to_f16(t[tx][ty + i * 8]);
}

// ---------------------------------------------------------------------------
// 256x256 B^T GEMM, K=2048 (T=64 tiles of BK=32), quad-buffered LDS (128 KB),
// REGISTER-PIPELINED: MFMA tile t from regs prefetched in iter t-1, while
// issuing ds_reads of tile t+1 and stage(t+3) — no waitcnt between ds_read
// issue and the MFMA cluster, so LDS reads execute under the MFMAs.
//   iter t: stage(t+3)->buf[(t+3)&3]; ds_read(t+1)->Rnxt; MFMA(Rcur);
//           lgkmcnt(0) [Rnxt loaded] + vmcnt(4) [tile t+2 landed, t+3 in
//           flight]; sched_barrier; s_barrier.
// Races: stage(t+3) overwrites buf[(t-1)&3]; tile t-1's frags were read in
// iter t-2, drained at its lgkmcnt(0) before its barrier -> safe. dsread(t+1)
// needs tile t+1 landed: guaranteed by iter t-1's vmcnt(4). Tail: body(61/62)
// use vmcnt(0) so tile 63 is landed before dsread(63).
// LDS swizzle (verified 0 conflicts in R3): stored slot = s ^ ((row>>1)&3),
// applied on the GLOBAL source, undone on ds_read; (row>>1)&3 is
// lane-constant on the read side -> offsets collapse to base + mi*512.
// XCD swizzle: bijective (nwg%8==0), each XCD gets a contiguous work chunk.
// ---------------------------------------------------------------------------
template<int MODE>
__global__ __launch_bounds__(512, 2)
void gemm256(const u16* __restrict__ A, const u16* __restrict__ Bt,
             const float* __restrict__ bias,
             float* __restrict__ Cf, u16* __restrict__ Ch,
             int N, int KB, long batchA, long batchB, long batchC)
{
  constexpr int KA = 2048;
  constexpr int T = 64;
  extern __shared__ u16 smem[];   // 4 bufs x (8192 A + 8192 B) u16 = 128 KB

  // XCD-aware bijective swizzle
  const int gx = gridDim.x, gy = gridDim.y;
  const int nwg = gx * gy * gridDim.z;
  const int flat = ((int)blockIdx.z * gy + blockIdx.y) * gx + blockIdx.x;
  const int qq = nwg >> 3;
  const int w = (flat & 7) * qq + (flat >> 3);
  const int by = w % gy;
  const int tmp = w / gy;
  const int bx = tmp % gx;
  const int z = tmp / gx;

  const u16* pA = A + (size_t)z * batchA;
  const u16* pB = Bt + (size_t)z * batchB;
  const int kmask = KB - 1;

  const int tid = threadIdx.x;
  const int lane = tid & 63;
  const int wave = tid >> 6;      // 0..7
  const int wr = wave >> 2;       // 0..1  (M)
  const int wc = wave & 3;        // 0..3  (N)
  const int m0 = bx * 256;
  const int n0 = by * 256;
  const int lr = lane & 15;
  const int ls = lane >> 4;

  // staging chunk coords: chunk c = 16B at LDS offset c*16; row=c>>2, slot=c&3
  const int c0 = tid, c1 = tid + 512;
  const int r0 = c0 >> 2, s0 = c0 & 3;
  const int r1 = c1 >> 2, s1 = c1 & 3;
  const int ga0 = ((s0 ^ ((r0 >> 1) & 3)) << 3);
  const int ga1 = ((s1 ^ ((r1 >> 1) & 3)) << 3);

  f32x4 acc[8][4];
  const f32x4 zero4 = {0.f, 0.f, 0.f, 0.f};
#pragma unroll
  for (int i = 0; i < 8; ++i)
#pragma unroll
    for (int j = 0; j < 4; ++j)
      acc[i][j] = zero4;

  // read-side offsets (elements); physical slot lane-constant
  const int slot8 = ((ls ^ ((lr >> 1) & 3)) << 3);
  const int baseA = (wr * 128 + lr) * 32 + slot8;
  const int baseB = 8192 + (wc * 64 + lr) * 32 + slot8;

  auto stage = [&](int t) {
    u16* b = smem + (t & 3) * 16384;
    const int kt = t * 32;
    const int ktb = kt & kmask;
    gload_lds16(pA + (size_t)(m0 + r0) * KA + kt + ga0, b + c0 * 8);
    gload_lds16(pA + (size_t)(m0 + r1) * KA + kt + ga1, b + c1 * 8);
    gload_lds16(pB + (size_t)(n0 + r0) * KB + ktb + ga0, b + 8192 + c0 * 8);
    gload_lds16(pB + (size_t)(n0 + r1) * KB + ktb + ga1, b + 8192 + c1 * 8);
  };

  auto dsread = [&](int t, f16x8* Af, f16x8* Bf) {
    const u16* cb = smem + (t & 3) * 16384;
#pragma unroll
    for (int mi = 0; mi < 8; ++mi)
      Af[mi] = *(const f16x8*)(cb + baseA + mi * 512);
#pragma unroll
    for (int ni = 0; ni < 4; ++ni)
      Bf[ni] = *(const f16x8*)(cb + baseB + ni * 512);
  };

  auto domfma = [&](f16x8* Af, f16x8* Bf) {
    __builtin_amdgcn_s_setprio(1);
#pragma unroll
    for (int ni = 0; ni < 4; ++ni)
#pragma unroll
      for (int mi = 0; mi < 8; ++mi)
        acc[mi][ni] = __builtin_amdgcn_mfma_f32_16x16x32_f16(Af[mi], Bf[ni], acc[mi][ni], 0, 0, 0);
    __builtin_amdgcn_s_setprio(0);
  };

  auto body = [&](int t, f16x8* cA, f16x8* cB, f16x8* nA, f16x8* nB, bool drain) {
    if (t + 3 < T) stage(t + 3);
    dsread(t + 1, nA, nB);
    domfma(cA, cB);
    if (drain) asm volatile("s_waitcnt vmcnt(0) lgkmcnt(0)" ::: "memory");
    else       asm volatile("s_waitcnt vmcnt(4) lgkmcnt(0)" ::: "memory");
    __builtin_amdgcn_sched_barrier(0);
    __builtin_amdgcn_s_barrier();
    __builtin_amdgcn_sched_barrier(0);
  };

  f16x8 RAa[8], RAb[4], RBa[8], RBb[4];

  // prologue: tiles 0,1,2 staged; wait 0,1 landed (tile 2 stays in flight)
  stage(0); stage(1); stage(2);
  asm volatile("s_waitcnt vmcnt(4)" ::: "memory");
  __builtin_amdgcn_s_barrier();
  __builtin_amdgcn_sched_barrier(0);
  dsread(0, RAa, RAb);

  for (int t = 0; t < 60; t += 2) {
    body(t,     RAa, RAb, RBa, RBb, false);
    body(t + 1, RBa, RBb, RAa, RAb, false);
  }
  body(60, RAa, RAb, RBa, RBb, false);
  body(61, RBa, RBb, RAa, RAb, true);   // drain: tile 63 must land
  body(62, RAa, RAb, RBa, RBb, true);
  domfma(RBa, RBb);                     // tile 63

  // epilogue: C/D layout: col = lane&15 (lr), row = ls*4 + r within frag
#pragma unroll
  for (int mi = 0; mi < 8; ++mi) {
#pragma unroll
    for (int ni = 0; ni < 4; ++ni) {
#pragma unroll
      for (int r = 0; r < 4; ++r) {
        int row = m0 + wr * 128 + mi * 16 + ls * 4 + r;
        int col = n0 + wc * 64 + ni * 16 + lr;
        float v = acc[mi][ni][r];
        if (MODE == 0) {
          v += bias[col];
          u16 h = f32_to_f16(v);
          u16 l = f32_to_f16(v - f16_to_f32(h));
          Ch[(size_t)row * (2 * N) + col] = h;
          Ch[(size_t)row * (2 * N) + N + col] = l;
        } else {
          Cf[(size_t)z * batchC + (size_t)row * N + col] = v;
        }
      }
    }
  }
}

// ---------------------------------------------------------------------------
// row softmax over Lk=2048, in place (fp32) + fp16 copy. 1 block (256t) / row.
// ---------------------------------------------------------------------------
__global__ __launch_bounds__(256)
void softmax_k(float* __restrict__ sc, u16* __restrict__ pf)
{
  __shared__ float redm[4], reds[4];
  size_t row = blockIdx.x;
  float* rp = sc + row * (size_t)LK;
  int tid = threadIdx.x;
  int lane = tid & 63, wv = tid >> 6;

  float4 v0 = *(const float4*)(rp + tid * 8);
  float4 v1 = *(const float4*)(rp + tid * 8 + 4);

  float m = fmaxf(fmaxf(fmaxf(v0.x, v0.y), fmaxf(v0.z, v0.w)),
                  fmaxf(fmaxf(v1.x, v1.y), fmaxf(v1.z, v1.w)));
#pragma unroll
  for (int off = 32; off > 0; off >>= 1)
    m = fmaxf(m, __shfl_xor(m, off));
  if (lane == 0) redm[wv] = m;
  __syncthreads();
  m = fmaxf(fmaxf(redm[0], redm[1]), fmaxf(redm[2], redm[3]));

  float e[8];
  e[0] = __expf(v0.x - m); e[1] = __expf(v0.y - m);
  e[2] = __expf(v0.z - m); e[3] = __expf(v0.w - m);
  e[4] = __expf(v1.x - m); e[5] = __expf(v1.y - m);
  e[6] = __expf(v1.z - m); e[7] = __expf(v1.w - m);
  float s = ((e[0] + e[1]) + (e[2] + e[3])) + ((e[4] + e[5]) + (e[6] + e[7]));
#pragma unroll
  for (int off = 32; off > 0; off >>= 1)
    s += __shfl_xor(s, off);
  if (lane == 0) reds[wv] = s;
  __syncthreads();
  s = (reds[0] + reds[1]) + (reds[2] + reds[3]);

  float inv = 1.0f / s;
  float4 p0 = {e[0] * inv, e[1] * inv, e[2] * inv, e[3] * inv};
  float4 p1 = {e[4] * inv, e[5] * inv, e[6] * inv, e[7] * inv};
  *(float4*)(rp + tid * 8) = p0;
  *(float4*)(rp + tid * 8 + 4) = p1;

  u16* pb = pf + row * (size_t)LK + tid * 8;
  ushort4 h0, h1;
  h0.x = f32_to_f16(p0.x); h0.y = f32_to_f16(p0.y);
  h0.z = f32_to_f16(p0.z); h0.w = f32_to_f16(p0.w);
  h1.x = f32_to_f16(p1.x); h1.y = f32_to_f16(p1.y);
  h1.z = f32_to_f16(p1.z); h1.w = f32_to_f16(p1.w);
  *(ushort4*)(pb) = h0;
  *(ushort4*)(pb + 4) = h1;
}

// ---------------------------------------------------------------------------
extern "C" void kernel_launch(void* const* d_in, const int* in_sizes, int n_in,
                              void* d_out, int out_size, void* d_ws, size_t ws_size,
                              hipStream_t stream)
{
  const float* q  = (const float*)d_in[0];
  const float* ky = (const float*)d_in[1];
  const float* vv = (const float*)d_in[2];
  const float* Ww = (const float*)d_in[3];
  const float* Wb = (const float*)d_in[4];
  float* out   = (float*)d_out;                       // [8,2048,1024]
  float* pattn = out + (size_t)B_SZ * LQ * HD;        // [8,2048,2048]

  char* ws = (char*)d_ws;
  u16* qs = (u16*)(ws);                               // q split-concat, 64 MB
  u16* kh = (u16*)(ws + 67108864);                    // key fp16, 32 MB
  u16* wh = (u16*)(ws + 100663296);                   // W fp16, 2 MB
  u16* vt = (u16*)(ws + 102760448);                   // V^T fp16, 32 MB
  u16* qp = (u16*)(ws + 136314880);                   // q_proj split-concat, 64 MB
  u16* pf = (u16*)(ws);                               // p fp16 (reuses qs)

  const int nq4 = (int)((size_t)B_SZ * LQ * HD / 4);  // 4,194,304
  const int nw4 = HD * HD / 4;                        // 262,144

  split_concat_k<<<2048, 256, 0, stream>>>((const float4*)q, qs, nq4);
  cvt_f16_k<<<2048, 256, 0, stream>>>((const float4*)ky, (ushort4*)kh, nq4);
  cvt_f16_k<<<1024, 256, 0, stream>>>((const float4*)Ww, (ushort4*)wh, nw4);
  vtrans_k<<<dim3(HD / 32, LK / 32, B_SZ), dim3(32, 8), 0, stream>>>(vv, vt);

  // GEMM1: q_proj = q @ W^T + b  (A = [qh|ql] K-concat, B masked k&1023)
  gemm256<0><<<dim3(64, 4, 1), 512, 131072, stream>>>(
      qs, wh, Wb, nullptr, qp,
      HD, HD, 0, 0, 0);

  // GEMM2: scores = q_proj @ key^T -> fp32 into p_attn region
  gemm256<1><<<dim3(8, 8, 8), 512, 131072, stream>>>(
      qp, kh, nullptr, pattn, nullptr,
      LK, HD, (long)LQ * 2 * HD, (long)LK * HD, (long)LQ * LK);

  // softmax rows, in place + fp16 copy for PV
  softmax_k<<<B_SZ * LQ, 256, 0, stream>>>(pattn, pf);

  // GEMM3: out = p @ V   (Vt is [HD][LK] per batch, KB=2048 -> mask no-op)
  gemm256<1><<<dim3(8, 4, 8), 512, 131072, stream>>>(
      pf, vt, nullptr, out, nullptr,
      HD, LK, (long)LQ * LK, (long)HD * LK, (long)LQ * HD);
}